// Round 1
// baseline (313.973 us; speedup 1.0000x reference)
//
#include <hip/hip_runtime.h>
#include <hip/hip_bf16.h>

using bf16 = __hip_bfloat16;
typedef __attribute__((ext_vector_type(8))) __bf16 bf16x8;
typedef __attribute__((ext_vector_type(4))) float f32x4;

#define B_   4
#define T_   2048
#define D_   1024
#define H_   16
#define HD_  64
#define BH_  (B_ * H_)
#define BT_  (B_ * T_)

// ---------------------------------------------------------------- cast fp32 -> bf16
__global__ void cast_kernel(const float* __restrict__ in, bf16* __restrict__ out, int n4) {
    int i = blockIdx.x * 256 + threadIdx.x;
    if (i >= n4) return;
    float4 v = reinterpret_cast<const float4*>(in)[i];
    union { bf16 h[4]; uint2 u; } tmp;
    tmp.h[0] = __float2bfloat16(v.x);
    tmp.h[1] = __float2bfloat16(v.y);
    tmp.h[2] = __float2bfloat16(v.z);
    tmp.h[3] = __float2bfloat16(v.w);
    reinterpret_cast<uint2*>(out)[i] = tmp.u;
}

// ---------------------------------------------------------------- W[K][N] fp32 -> Wt[N][K] bf16
__global__ void transpose_cast(const float* __restrict__ W, bf16* __restrict__ Wt,
                               int K, int N) {
    __shared__ float tile[32][33];
    int nb = blockIdx.x * 32, kb = blockIdx.y * 32;
    int tx = threadIdx.x, ty = threadIdx.y;   // 32 x 8
    #pragma unroll
    for (int i = 0; i < 32; i += 8)
        tile[ty + i][tx] = W[(size_t)(kb + ty + i) * N + nb + tx];
    __syncthreads();
    #pragma unroll
    for (int i = 0; i < 32; i += 8)
        Wt[(size_t)(nb + ty + i) * K + kb + tx] = __float2bfloat16(tile[tx][ty + i]);
}

// ---------------------------------------------------------------- GEMM  C = A @ Bt^T (+bias)
// A: [M][K] bf16 row-major, Bt: [N][K] bf16 row-major (i.e., B transposed).
// MODE 0: QKV epilogue -> scatter to Q ([bh][t][64], *0.125), K ([bh][t][64]), V^T ([bh][64][t])
// MODE 1: proj epilogue -> fp32 out[row][col] = acc + bias[col]
template <int MODE>
__global__ __launch_bounds__(256)
void gemm_bt(const bf16* __restrict__ A, const bf16* __restrict__ Bt,
             const float* __restrict__ bias,
             bf16* __restrict__ Qo, bf16* __restrict__ Ko, bf16* __restrict__ Vo,
             float* __restrict__ Fo, int K) {
    const int bm = blockIdx.x * 128;
    const int bn = blockIdx.y * 128;
    const int tid  = threadIdx.x;
    const int wave = tid >> 6;
    const int lane = tid & 63;
    const int wr = (wave >> 1) * 64;
    const int wc = (wave & 1) * 64;
    const int ln_g = lane >> 4;    // 0..3
    const int ln_c = lane & 15;    // 0..15

    __shared__ bf16 As[128][72];
    __shared__ bf16 Bs[128][72];

    f32x4 acc[4][4] = {};

    const int srow = tid >> 3;          // 0..31
    const int scol = (tid & 7) * 8;     // 0,8,..,56

    for (int k0 = 0; k0 < K; k0 += 64) {
        __syncthreads();
        #pragma unroll
        for (int i = 0; i < 4; ++i) {
            int r = srow + 32 * i;
            *reinterpret_cast<int4*>(&As[r][scol]) =
                *reinterpret_cast<const int4*>(&A[(size_t)(bm + r) * K + k0 + scol]);
            *reinterpret_cast<int4*>(&Bs[r][scol]) =
                *reinterpret_cast<const int4*>(&Bt[(size_t)(bn + r) * K + k0 + scol]);
        }
        __syncthreads();
        #pragma unroll
        for (int ks = 0; ks < 2; ++ks) {
            bf16x8 af[4], bfr[4];
            #pragma unroll
            for (int m = 0; m < 4; ++m)
                af[m] = *reinterpret_cast<const bf16x8*>(&As[wr + m * 16 + ln_c][ks * 32 + ln_g * 8]);
            #pragma unroll
            for (int n = 0; n < 4; ++n)
                bfr[n] = *reinterpret_cast<const bf16x8*>(&Bs[wc + n * 16 + ln_c][ks * 32 + ln_g * 8]);
            #pragma unroll
            for (int m = 0; m < 4; ++m)
                #pragma unroll
                for (int n = 0; n < 4; ++n)
                    acc[m][n] = __builtin_amdgcn_mfma_f32_16x16x32_bf16(af[m], bfr[n], acc[m][n], 0, 0, 0);
        }
    }

    #pragma unroll
    for (int m = 0; m < 4; ++m) {
        #pragma unroll
        for (int n = 0; n < 4; ++n) {
            const int col = bn + wc + n * 16 + ln_c;
            const float bcol = bias[col];
            #pragma unroll
            for (int j = 0; j < 4; ++j) {
                const int row = bm + wr + m * 16 + ln_g * 4 + j;
                float v = acc[m][n][j] + bcol;
                if (MODE == 0) {
                    const int part = col >> 10;       // 0=q 1=k 2=v
                    const int cc = col & 1023;
                    const int h = cc >> 6, d = cc & 63;
                    const int b = row >> 11, t = row & 2047;
                    const int bh = b * H_ + h;
                    if (part == 0)
                        Qo[((size_t)bh * T_ + t) * HD_ + d] = __float2bfloat16(v * 0.125f);
                    else if (part == 1)
                        Ko[((size_t)bh * T_ + t) * HD_ + d] = __float2bfloat16(v);
                    else
                        Vo[((size_t)bh * HD_ + d) * T_ + t] = __float2bfloat16(v);
                } else {
                    Fo[(size_t)row * D_ + col] = v;
                }
            }
        }
    }
}

// ---------------------------------------------------------------- causal flash attention
// Q,K: [bh][t][64] bf16 (Q pre-scaled by 1/8). Vt: [bh][64][t] bf16.
// ctx out: [b*T + t][h*64 + d] bf16.
__global__ __launch_bounds__(256)
void attn_kernel(const bf16* __restrict__ Q, const bf16* __restrict__ K,
                 const bf16* __restrict__ Vt, bf16* __restrict__ ctx) {
    const int bh = blockIdx.x;       // 0..63
    const int qt = blockIdx.y;       // 0..31
    const int qbase = qt * 64;
    const int tid  = threadIdx.x;
    const int wave = tid >> 6;
    const int lane = tid & 63;
    const int ln_g = lane >> 4;
    const int ln_c = lane & 15;

    const bf16* Qp = Q  + (size_t)bh * T_ * HD_;
    const bf16* Kp = K  + (size_t)bh * T_ * HD_;
    const bf16* Vp = Vt + (size_t)bh * HD_ * T_;

    __shared__ bf16 Ks[32][72];
    __shared__ bf16 Vs[64][40];
    __shared__ bf16 Ps[4][16][40];

    // Q fragments (A-frag: row = lane&15, k = (lane>>4)*8 + j)
    const int qrow = qbase + wave * 16 + ln_c;
    bf16x8 qf0 = *reinterpret_cast<const bf16x8*>(&Qp[(size_t)qrow * HD_ + ln_g * 8]);
    bf16x8 qf1 = *reinterpret_cast<const bf16x8*>(&Qp[(size_t)qrow * HD_ + 32 + ln_g * 8]);

    f32x4 o[4] = {};
    float mr[4] = {-INFINITY, -INFINITY, -INFINITY, -INFINITY};
    float lsum[4] = {0.f, 0.f, 0.f, 0.f};

    const int qwave_max = qbase + wave * 16 + 15;
    const int sr = tid >> 3;           // 0..31
    const int sc = (tid & 7) * 8;
    const int vr = tid >> 2;           // 0..63
    const int vc = (tid & 3) * 8;

    const int kend = qbase + 64;
    for (int kb = 0; kb < kend; kb += 32) {
        __syncthreads();
        *reinterpret_cast<int4*>(&Ks[sr][sc]) =
            *reinterpret_cast<const int4*>(&Kp[(size_t)(kb + sr) * HD_ + sc]);
        *reinterpret_cast<int4*>(&Vs[vr][vc]) =
            *reinterpret_cast<const int4*>(&Vp[(size_t)vr * T_ + kb + vc]);
        __syncthreads();
        if (kb > qwave_max) continue;   // fully masked for this wave

        // S = Q K^T  (16 q-rows x 32 k-cols, per wave)
        f32x4 s0 = {0.f, 0.f, 0.f, 0.f}, s1 = {0.f, 0.f, 0.f, 0.f};
        {
            bf16x8 k00 = *reinterpret_cast<const bf16x8*>(&Ks[ln_c][ln_g * 8]);
            bf16x8 k10 = *reinterpret_cast<const bf16x8*>(&Ks[16 + ln_c][ln_g * 8]);
            s0 = __builtin_amdgcn_mfma_f32_16x16x32_bf16(qf0, k00, s0, 0, 0, 0);
            s1 = __builtin_amdgcn_mfma_f32_16x16x32_bf16(qf0, k10, s1, 0, 0, 0);
            bf16x8 k01 = *reinterpret_cast<const bf16x8*>(&Ks[ln_c][32 + ln_g * 8]);
            bf16x8 k11 = *reinterpret_cast<const bf16x8*>(&Ks[16 + ln_c][32 + ln_g * 8]);
            s0 = __builtin_amdgcn_mfma_f32_16x16x32_bf16(qf1, k01, s0, 0, 0, 0);
            s1 = __builtin_amdgcn_mfma_f32_16x16x32_bf16(qf1, k11, s1, 0, 0, 0);
        }
        // online softmax (row r = ln_g*4 + j lives in the 16 lanes sharing ln_g)
        #pragma unroll
        for (int j = 0; j < 4; ++j) {
            const int qj = qbase + wave * 16 + ln_g * 4 + j;
            if (kb + ln_c > qj)      s0[j] = -INFINITY;
            if (kb + 16 + ln_c > qj) s1[j] = -INFINITY;
            float mx = fmaxf(s0[j], s1[j]);
            #pragma unroll
            for (int off = 1; off < 16; off <<= 1)
                mx = fmaxf(mx, __shfl_xor(mx, off));
            const float mnew = fmaxf(mr[j], mx);
            const float alpha = __expf(mr[j] - mnew);
            const float p0 = __expf(s0[j] - mnew);
            const float p1 = __expf(s1[j] - mnew);
            float rs = p0 + p1;
            #pragma unroll
            for (int off = 1; off < 16; off <<= 1)
                rs += __shfl_xor(rs, off);
            lsum[j] = lsum[j] * alpha + rs;
            mr[j] = mnew;
            o[0][j] *= alpha; o[1][j] *= alpha; o[2][j] *= alpha; o[3][j] *= alpha;
            Ps[wave][ln_g * 4 + j][ln_c]      = __float2bfloat16(p0);
            Ps[wave][ln_g * 4 + j][16 + ln_c] = __float2bfloat16(p1);
        }
        // PV: A = P (16x32) from LDS, B = V (32x16 tiles) from Vs (d-major)
        bf16x8 pf = *reinterpret_cast<const bf16x8*>(&Ps[wave][ln_c][ln_g * 8]);
        #pragma unroll
        for (int d0 = 0; d0 < 4; ++d0) {
            bf16x8 vf = *reinterpret_cast<const bf16x8*>(&Vs[d0 * 16 + ln_c][ln_g * 8]);
            o[d0] = __builtin_amdgcn_mfma_f32_16x16x32_bf16(pf, vf, o[d0], 0, 0, 0);
        }
    }

    // epilogue: ctx[(b*T + t)][h*64 + d]
    const int b = bh >> 4, h = bh & 15;
    #pragma unroll
    for (int j = 0; j < 4; ++j) {
        const float inv = 1.0f / lsum[j];
        const int t = qbase + wave * 16 + ln_g * 4 + j;
        bf16* dst = ctx + ((size_t)(b * T_ + t)) * D_ + h * HD_;
        #pragma unroll
        for (int d0 = 0; d0 < 4; ++d0)
            dst[d0 * 16 + ln_c] = __float2bfloat16(o[d0][j] * inv);
    }
}

// ---------------------------------------------------------------- launch
extern "C" void kernel_launch(void* const* d_in, const int* in_sizes, int n_in,
                              void* d_out, int out_size, void* d_ws, size_t ws_size,
                              hipStream_t stream) {
    const float* x      = (const float*)d_in[0];
    const float* W_attn = (const float*)d_in[1];
    const float* b_attn = (const float*)d_in[2];
    const float* W_proj = (const float*)d_in[3];
    const float* b_proj = (const float*)d_in[4];
    float* out = (float*)d_out;

    char* ws = (char*)d_ws;
    bf16* xh  = (bf16*)ws;  ws += (size_t)BT_ * D_ * 2;
    bf16* WaT = (bf16*)ws;  ws += (size_t)3 * D_ * D_ * 2;
    bf16* WpT = (bf16*)ws;  ws += (size_t)D_ * D_ * 2;
    bf16* Qb  = (bf16*)ws;  ws += (size_t)BH_ * T_ * HD_ * 2;
    bf16* Kb  = (bf16*)ws;  ws += (size_t)BH_ * T_ * HD_ * 2;
    bf16* Vb  = (bf16*)ws;  ws += (size_t)BH_ * T_ * HD_ * 2;
    bf16* ctx = (bf16*)ws;  ws += (size_t)BT_ * D_ * 2;

    cast_kernel<<<(BT_ * D_ / 4 + 255) / 256, 256, 0, stream>>>(x, xh, BT_ * D_ / 4);
    transpose_cast<<<dim3(3 * D_ / 32, D_ / 32), dim3(32, 8), 0, stream>>>(W_attn, WaT, D_, 3 * D_);
    transpose_cast<<<dim3(D_ / 32, D_ / 32), dim3(32, 8), 0, stream>>>(W_proj, WpT, D_, D_);

    gemm_bt<0><<<dim3(BT_ / 128, 3 * D_ / 128), 256, 0, stream>>>(
        xh, WaT, b_attn, Qb, Kb, Vb, nullptr, D_);

    attn_kernel<<<dim3(BH_, T_ / 64), 256, 0, stream>>>(Qb, Kb, Vb, ctx);

    gemm_bt<1><<<dim3(BT_ / 128, D_ / 128), 256, 0, stream>>>(
        ctx, WpT, b_proj, nullptr, nullptr, nullptr, out, D_);
}

// Round 3
// 203.526 us; speedup vs baseline: 1.5427x; 1.5427x over previous
//
#include <hip/hip_runtime.h>
#include <hip/hip_bf16.h>

using bf16 = __hip_bfloat16;
typedef __attribute__((ext_vector_type(8))) __bf16 bf16x8;
typedef __attribute__((ext_vector_type(4))) float f32x4;

#define B_   4
#define T_   2048
#define D_   1024
#define H_   16
#define HD_  64
#define BH_  (B_ * H_)
#define BT_  (B_ * T_)

// ---------------------------------------------------------------- cast fp32 -> bf16
__global__ void cast_kernel(const float* __restrict__ in, bf16* __restrict__ out, int n4) {
    int i = blockIdx.x * 256 + threadIdx.x;
    if (i >= n4) return;
    float4 v = reinterpret_cast<const float4*>(in)[i];
    union { bf16 h[4]; uint2 u; } tmp;
    tmp.h[0] = __float2bfloat16(v.x);
    tmp.h[1] = __float2bfloat16(v.y);
    tmp.h[2] = __float2bfloat16(v.z);
    tmp.h[3] = __float2bfloat16(v.w);
    reinterpret_cast<uint2*>(out)[i] = tmp.u;
}

// ---------------------------------------------------------------- W[K][N] fp32 -> Wt[N][K] bf16
__global__ void transpose_cast(const float* __restrict__ W, bf16* __restrict__ Wt,
                               int K, int N) {
    __shared__ float tile[32][33];
    int nb = blockIdx.x * 32, kb = blockIdx.y * 32;
    int tx = threadIdx.x, ty = threadIdx.y;   // 32 x 8
    #pragma unroll
    for (int i = 0; i < 32; i += 8)
        tile[ty + i][tx] = W[(size_t)(kb + ty + i) * N + nb + tx];
    __syncthreads();
    #pragma unroll
    for (int i = 0; i < 32; i += 8)
        Wt[(size_t)(nb + ty + i) * K + kb + tx] = __float2bfloat16(tile[tx][ty + i]);
}

// ---------------------------------------------------------------- GEMM  C = A @ Bt^T (+bias)
// A: [M][K] bf16 row-major, Bt: [N][K] bf16 row-major (i.e., B transposed).
// MODE 0: QKV epilogue -> scatter to Q ([bh][t][64], *0.125), K ([bh][t][64]), V^T ([bh][64][t])
// MODE 1: proj epilogue -> fp32 out[row][col] = acc + bias[col]
template <int MODE>
__global__ __launch_bounds__(256)
void gemm_bt(const bf16* __restrict__ A, const bf16* __restrict__ Bt,
             const float* __restrict__ bias,
             bf16* __restrict__ Qo, bf16* __restrict__ Ko, bf16* __restrict__ Vo,
             float* __restrict__ Fo, int K) {
    const int bm = blockIdx.x * 128;
    const int bn = blockIdx.y * 128;
    const int tid  = threadIdx.x;
    const int wave = tid >> 6;
    const int lane = tid & 63;
    const int wr = (wave >> 1) * 64;
    const int wc = (wave & 1) * 64;
    const int ln_g = lane >> 4;    // 0..3
    const int ln_c = lane & 15;    // 0..15

    __shared__ bf16 As[128][72];
    __shared__ bf16 Bs[128][72];

    f32x4 acc[4][4] = {};

    const int srow = tid >> 3;          // 0..31
    const int scol = (tid & 7) * 8;     // 0,8,..,56

    for (int k0 = 0; k0 < K; k0 += 64) {
        __syncthreads();
        #pragma unroll
        for (int i = 0; i < 4; ++i) {
            int r = srow + 32 * i;
            *reinterpret_cast<int4*>(&As[r][scol]) =
                *reinterpret_cast<const int4*>(&A[(size_t)(bm + r) * K + k0 + scol]);
            *reinterpret_cast<int4*>(&Bs[r][scol]) =
                *reinterpret_cast<const int4*>(&Bt[(size_t)(bn + r) * K + k0 + scol]);
        }
        __syncthreads();
        #pragma unroll
        for (int ks = 0; ks < 2; ++ks) {
            bf16x8 af[4], bfr[4];
            #pragma unroll
            for (int m = 0; m < 4; ++m)
                af[m] = *reinterpret_cast<const bf16x8*>(&As[wr + m * 16 + ln_c][ks * 32 + ln_g * 8]);
            #pragma unroll
            for (int n = 0; n < 4; ++n)
                bfr[n] = *reinterpret_cast<const bf16x8*>(&Bs[wc + n * 16 + ln_c][ks * 32 + ln_g * 8]);
            #pragma unroll
            for (int m = 0; m < 4; ++m)
                #pragma unroll
                for (int n = 0; n < 4; ++n)
                    acc[m][n] = __builtin_amdgcn_mfma_f32_16x16x32_bf16(af[m], bfr[n], acc[m][n], 0, 0, 0);
        }
    }

    #pragma unroll
    for (int m = 0; m < 4; ++m) {
        #pragma unroll
        for (int n = 0; n < 4; ++n) {
            const int col = bn + wc + n * 16 + ln_c;
            const float bcol = bias[col];
            #pragma unroll
            for (int j = 0; j < 4; ++j) {
                const int row = bm + wr + m * 16 + ln_g * 4 + j;
                float v = acc[m][n][j] + bcol;
                if (MODE == 0) {
                    const int part = col >> 10;       // 0=q 1=k 2=v
                    const int cc = col & 1023;
                    const int h = cc >> 6, d = cc & 63;
                    const int b = row >> 11, t = row & 2047;
                    const int bh = b * H_ + h;
                    if (part == 0)
                        Qo[((size_t)bh * T_ + t) * HD_ + d] = __float2bfloat16(v * 0.125f);
                    else if (part == 1)
                        Ko[((size_t)bh * T_ + t) * HD_ + d] = __float2bfloat16(v);
                    else
                        Vo[((size_t)bh * HD_ + d) * T_ + t] = __float2bfloat16(v);
                } else {
                    Fo[(size_t)row * D_ + col] = v;
                }
            }
        }
    }
}

// ---------------------------------------------------------------- causal flash attention v2
// Swapped-operand: S^T = mfma(K, Q) so q = lane&15 (running m/l are lane-scalars);
// O^T = mfma(V^T, P^T) so the alpha rescale is also lane-local.
// Q,K: [bh][t][64] bf16 (Q pre-scaled by 1/8). Vt: [bh][64][t] bf16.
// ctx out: [b*T + t][h*64 + d] bf16.
// Grid: (BH, 16 pairs). Block processes q-tiles {p, 31-p}: exactly 33 kv-iters each.
__global__ __launch_bounds__(256)
void attn_kernel(const bf16* __restrict__ Q, const bf16* __restrict__ K,
                 const bf16* __restrict__ Vt, bf16* __restrict__ ctx) {
    const int bh = blockIdx.x;       // 0..63
    const int pr = blockIdx.y;       // 0..15
    const int tid  = threadIdx.x;
    const int wave = tid >> 6;
    const int lane = tid & 63;
    const int ln_g = lane >> 4;      // 0..3
    const int ln_c = lane & 15;      // 0..15

    const bf16* Qp = Q  + (size_t)bh * T_ * HD_;
    const bf16* Kp = K  + (size_t)bh * T_ * HD_;
    const bf16* Vp = Vt + (size_t)bh * HD_ * T_;

    __shared__ bf16 Ks[64][72];
    __shared__ bf16 Vs[64][72];
    __shared__ bf16 Ps[4][16][72];

    const int srow = tid >> 3;       // 0..31
    const int sc8  = (tid & 7) * 8;  // 0..56

    const int b = bh >> 4, h = bh & 15;

    #pragma unroll
    for (int s = 0; s < 2; ++s) {
        const int qt = (s == 0) ? pr : (31 - pr);
        const int qbase = qt * 64;
        const int qglob = qbase + wave * 16 + ln_c;    // this lane's q row

        // Q fragments (B-operand: col=q=ln_c, k-elem=ln_g*8+j)
        const bf16x8 qf0 = *reinterpret_cast<const bf16x8*>(&Qp[(size_t)qglob * HD_ + ln_g * 8]);
        const bf16x8 qf1 = *reinterpret_cast<const bf16x8*>(&Qp[(size_t)qglob * HD_ + 32 + ln_g * 8]);

        f32x4 o[4] = {};                // o[dtile][j] = O^T[dtile*16 + ln_g*4 + j][q=ln_c]
        float m = -INFINITY, l = 0.f;

        const int nk = qt + 1;          // 64-wide kv tiles

        // ---- prologue: stage tile 0
        int4 kr0, kr1, vr0, vr1;
        {
            kr0 = *reinterpret_cast<const int4*>(&Kp[(size_t)srow * HD_ + sc8]);
            kr1 = *reinterpret_cast<const int4*>(&Kp[(size_t)(srow + 32) * HD_ + sc8]);
            vr0 = *reinterpret_cast<const int4*>(&Vp[(size_t)srow * T_ + sc8]);
            vr1 = *reinterpret_cast<const int4*>(&Vp[(size_t)(srow + 32) * T_ + sc8]);
        }
        __syncthreads();   // previous tile's LDS reads complete
        *reinterpret_cast<int4*>(&Ks[srow][sc8])      = kr0;
        *reinterpret_cast<int4*>(&Ks[srow + 32][sc8]) = kr1;
        *reinterpret_cast<int4*>(&Vs[srow][sc8])      = vr0;
        *reinterpret_cast<int4*>(&Vs[srow + 32][sc8]) = vr1;
        __syncthreads();

        for (int it = 0; it < nk; ++it) {
            const int kb = it * 64;
            const bool notlast = (it + 1 < nk);
            if (notlast) {   // async-stage split: issue next tile's loads now
                const int kn = kb + 64;
                kr0 = *reinterpret_cast<const int4*>(&Kp[(size_t)(kn + srow) * HD_ + sc8]);
                kr1 = *reinterpret_cast<const int4*>(&Kp[(size_t)(kn + srow + 32) * HD_ + sc8]);
                vr0 = *reinterpret_cast<const int4*>(&Vp[(size_t)srow * T_ + kn + sc8]);
                vr1 = *reinterpret_cast<const int4*>(&Vp[(size_t)(srow + 32) * T_ + kn + sc8]);
            }

            // ---- S^T = K Q^T : st[kk][j] <-> k = kb + kk*16 + ln_g*4 + j, q = qglob
            f32x4 st[4];
            #pragma unroll
            for (int kk = 0; kk < 4; ++kk) {
                bf16x8 kfa = *reinterpret_cast<const bf16x8*>(&Ks[kk * 16 + ln_c][ln_g * 8]);
                bf16x8 kfb = *reinterpret_cast<const bf16x8*>(&Ks[kk * 16 + ln_c][32 + ln_g * 8]);
                f32x4 z = {0.f, 0.f, 0.f, 0.f};
                z = __builtin_amdgcn_mfma_f32_16x16x32_bf16(kfa, qf0, z, 0, 0, 0);
                z = __builtin_amdgcn_mfma_f32_16x16x32_bf16(kfb, qf1, z, 0, 0, 0);
                st[kk] = z;
            }

            if (!notlast) {   // diagonal tile: causal mask
                #pragma unroll
                for (int kk = 0; kk < 4; ++kk)
                    #pragma unroll
                    for (int j = 0; j < 4; ++j)
                        if (kb + kk * 16 + ln_g * 4 + j > qglob) st[kk][j] = -INFINITY;
            }

            // ---- online softmax (q is lane-local; reduce over 4 ln_g groups only)
            float mx = -INFINITY;
            #pragma unroll
            for (int kk = 0; kk < 4; ++kk)
                #pragma unroll
                for (int j = 0; j < 4; ++j)
                    mx = fmaxf(mx, st[kk][j]);
            mx = fmaxf(mx, __shfl_xor(mx, 16));
            mx = fmaxf(mx, __shfl_xor(mx, 32));
            const float mnew = fmaxf(m, mx);
            const float alpha = __expf(m - mnew);
            float rs = 0.f;
            #pragma unroll
            for (int kk = 0; kk < 4; ++kk) {
                union { bf16 hh[4]; uint2 u; } pk;
                #pragma unroll
                for (int j = 0; j < 4; ++j) {
                    float p = __expf(st[kk][j] - mnew);
                    rs += p;
                    pk.hh[j] = __float2bfloat16(p);
                }
                *reinterpret_cast<uint2*>(&Ps[wave][ln_c][kk * 16 + ln_g * 4]) = pk.u;
            }
            rs += __shfl_xor(rs, 16);
            rs += __shfl_xor(rs, 32);
            l = l * alpha + rs;
            m = mnew;
            #pragma unroll
            for (int dt = 0; dt < 4; ++dt)
                #pragma unroll
                for (int j = 0; j < 4; ++j)
                    o[dt][j] *= alpha;

            // ---- O^T += V^T P^T  (A = V^T frag from Vs, B = P^T frag from Ps)
            const bf16x8 pf0 = *reinterpret_cast<const bf16x8*>(&Ps[wave][ln_c][ln_g * 8]);
            const bf16x8 pf1 = *reinterpret_cast<const bf16x8*>(&Ps[wave][ln_c][32 + ln_g * 8]);
            #pragma unroll
            for (int dt = 0; dt < 4; ++dt) {
                bf16x8 vfa = *reinterpret_cast<const bf16x8*>(&Vs[dt * 16 + ln_c][ln_g * 8]);
                bf16x8 vfb = *reinterpret_cast<const bf16x8*>(&Vs[dt * 16 + ln_c][32 + ln_g * 8]);
                o[dt] = __builtin_amdgcn_mfma_f32_16x16x32_bf16(vfa, pf0, o[dt], 0, 0, 0);
                o[dt] = __builtin_amdgcn_mfma_f32_16x16x32_bf16(vfb, pf1, o[dt], 0, 0, 0);
            }

            if (notlast) {
                __syncthreads();   // all waves done reading current LDS tile
                *reinterpret_cast<int4*>(&Ks[srow][sc8])      = kr0;
                *reinterpret_cast<int4*>(&Ks[srow + 32][sc8]) = kr1;
                *reinterpret_cast<int4*>(&Vs[srow][sc8])      = vr0;
                *reinterpret_cast<int4*>(&Vs[srow + 32][sc8]) = vr1;
                __syncthreads();
            }
        }

        // ---- epilogue: O^T[d][q] -> ctx[b*T + q][h*64 + d]
        const float inv = 1.0f / l;
        bf16* dst = ctx + ((size_t)(b * T_ + qglob)) * D_ + h * HD_;
        #pragma unroll
        for (int dt = 0; dt < 4; ++dt) {
            union { bf16 hh[4]; uint2 u; } ok;
            #pragma unroll
            for (int j = 0; j < 4; ++j)
                ok.hh[j] = __float2bfloat16(o[dt][j] * inv);
            *reinterpret_cast<uint2*>(&dst[dt * 16 + ln_g * 4]) = ok.u;
        }
    }
}

// ---------------------------------------------------------------- launch
extern "C" void kernel_launch(void* const* d_in, const int* in_sizes, int n_in,
                              void* d_out, int out_size, void* d_ws, size_t ws_size,
                              hipStream_t stream) {
    const float* x      = (const float*)d_in[0];
    const float* W_attn = (const float*)d_in[1];
    const float* b_attn = (const float*)d_in[2];
    const float* W_proj = (const float*)d_in[3];
    const float* b_proj = (const float*)d_in[4];
    float* out = (float*)d_out;

    char* ws = (char*)d_ws;
    bf16* xh  = (bf16*)ws;  ws += (size_t)BT_ * D_ * 2;
    bf16* WaT = (bf16*)ws;  ws += (size_t)3 * D_ * D_ * 2;
    bf16* WpT = (bf16*)ws;  ws += (size_t)D_ * D_ * 2;
    bf16* Qb  = (bf16*)ws;  ws += (size_t)BH_ * T_ * HD_ * 2;
    bf16* Kb  = (bf16*)ws;  ws += (size_t)BH_ * T_ * HD_ * 2;
    bf16* Vb  = (bf16*)ws;  ws += (size_t)BH_ * T_ * HD_ * 2;
    bf16* ctx = (bf16*)ws;  ws += (size_t)BT_ * D_ * 2;

    cast_kernel<<<(BT_ * D_ / 4 + 255) / 256, 256, 0, stream>>>(x, xh, BT_ * D_ / 4);
    transpose_cast<<<dim3(3 * D_ / 32, D_ / 32), dim3(32, 8), 0, stream>>>(W_attn, WaT, D_, 3 * D_);
    transpose_cast<<<dim3(D_ / 32, D_ / 32), dim3(32, 8), 0, stream>>>(W_proj, WpT, D_, D_);

    gemm_bt<0><<<dim3(BT_ / 128, 3 * D_ / 128), 256, 0, stream>>>(
        xh, WaT, b_attn, Qb, Kb, Vb, nullptr, D_);

    attn_kernel<<<dim3(BH_, 16), 256, 0, stream>>>(Qb, Kb, Vb, ctx);

    gemm_bt<1><<<dim3(BT_ / 128, D_ / 128), 256, 0, stream>>>(
        ctx, WpT, b_proj, nullptr, nullptr, nullptr, out, D_);
}